// Round 10
// baseline (355.368 us; speedup 1.0000x reference)
//
#include <hip/hip_runtime.h>
#include <hip/hip_cooperative_groups.h>
#include <hip/hip_bf16.h>
#include <math.h>

namespace cg = cooperative_groups;

#define DD 256
#define BB 8
#define TT 1024
#define MM (BB*TT)
#define NH 4
#define DKH 64
#define NQ 3
#define SPLIT 32
#define SROWS (TT/SPLIT)   // 32

typedef __attribute__((ext_vector_type(8))) short bf16x8;
typedef __attribute__((ext_vector_type(4))) float f32x4;
typedef unsigned short u16;
typedef unsigned int u32;

__device__ __forceinline__ float bf2f(u16 u) {
  return __uint_as_float(((u32)u) << 16);
}
__device__ __forceinline__ u16 f2bf(float x) {
  __hip_bfloat16 h = __float2bfloat16(x);
  return *reinterpret_cast<u16*>(&h);
}
__device__ __forceinline__ uint2 pack4(float a, float b, float c, float d) {
  uint2 r;
  r.x = (u32)f2bf(a) | ((u32)f2bf(b) << 16);
  r.y = (u32)f2bf(c) | ((u32)f2bf(d) << 16);
  return r;
}
__device__ __forceinline__ float wred(float v) {
#pragma unroll
  for (int off = 32; off; off >>= 1) v += __shfl_xor(v, off);
  return v;
}

struct TParams {
  const float* x;
  const float* f1w; const float* f1b;
  const float* f2w; const float* f2b;
  const float* gw;  const float* gb;
  const float* lng; const float* lnb;
  const float* wq;  const float* wk;  const float* wv;
  const float* wow; const float* wob;
  const float* alng; const float* alnb;
  const float* g2f1w; const float* g2f1b;
  const float* g2f2w; const float* g2f2b;
  const float* g2gw;  const float* g2gb;
  const float* g2lng; const float* g2lnb;
  const float* qhw;   const float* qhb;
  u16* eta1; u16* eta2; u16* hbuf; float* hlast;
  float* qkbuf; u16* wbf; float* p_eh; float* p_den;
  float* out;
};

// ============================ phase: 64x64 GEMM ============================
// bid in [0,512): m0=(bid>>2)*64, n0=(bid&3)*64. smem >= 67584 B.
template<bool ABF, int ACT>
__device__ __forceinline__ void gemm_phase(char* smem, const void* A_,
                                           const float* W, const float* bias,
                                           u16* out, int bid, int tid)
{
  u16 (*As)[264] = reinterpret_cast<u16(*)[264]>(smem);
  u16 (*Bs)[264] = reinterpret_cast<u16(*)[264]>(smem + 33792);
  const int lane = tid & 63, wave = tid >> 6;
  const int wr = wave >> 1, wc = wave & 1;
  const int q  = lane >> 4, lr = lane & 15;
  const int m0 = (bid >> 2) * 64, n0 = (bid & 3) * 64;

#pragma unroll
  for (int p = 0; p < 8; ++p) {
    const int c = tid + p * 256;
    const int row = c >> 5, col = (c & 31) * 8;
    if constexpr (ABF) {
      *(uint4*)&As[row][col] = *(const uint4*)((const u16*)A_ + (size_t)(m0 + row) * DD + col);
    } else {
      const float* ap = (const float*)A_ + (size_t)(m0 + row) * DD + col;
      const float4 v0 = *(const float4*)ap, v1 = *(const float4*)(ap + 4);
      *(uint2*)&As[row][col]     = pack4(v0.x, v0.y, v0.z, v0.w);
      *(uint2*)&As[row][col + 4] = pack4(v1.x, v1.y, v1.z, v1.w);
    }
    const float* wp = W + (size_t)(n0 + row) * DD + col;
    const float4 w0 = *(const float4*)wp, w1 = *(const float4*)(wp + 4);
    *(uint2*)&Bs[row][col]     = pack4(w0.x, w0.y, w0.z, w0.w);
    *(uint2*)&Bs[row][col + 4] = pack4(w1.x, w1.y, w1.z, w1.w);
  }
  __syncthreads();

  f32x4 acc[2][2] = {};
#pragma unroll
  for (int kk = 0; kk < 8; ++kk) {
    const int koff = kk * 32 + q * 8;
    bf16x8 av[2], bv[2];
    av[0] = *(const bf16x8*)&As[wr * 32 + lr][koff];
    av[1] = *(const bf16x8*)&As[wr * 32 + 16 + lr][koff];
    bv[0] = *(const bf16x8*)&Bs[wc * 32 + lr][koff];
    bv[1] = *(const bf16x8*)&Bs[wc * 32 + 16 + lr][koff];
#pragma unroll
    for (int i = 0; i < 2; ++i)
#pragma unroll
      for (int j = 0; j < 2; ++j)
        acc[i][j] = __builtin_amdgcn_mfma_f32_16x16x32_bf16(av[i], bv[j], acc[i][j], 0, 0, 0);
  }

#pragma unroll
  for (int i = 0; i < 2; ++i) {
#pragma unroll
    for (int j = 0; j < 2; ++j) {
      const int col = n0 + wc * 32 + j * 16 + lr;
      const float bvv = bias ? bias[col] : 0.f;
#pragma unroll
      for (int t = 0; t < 4; ++t) {
        const int row = m0 + wr * 32 + i * 16 + q * 4 + t;
        float v = acc[i][j][t] + bvv;
        if (ACT == 1) v = v > 0.f ? v : expm1f(v);
        out[(size_t)row * DD + col] = f2bf(v);
      }
    }
  }
}

// ============================ phase: GRN gate+LN (+qk) =====================
// bid in [0,256): 32 rows each. smem >= 79872 B.
__device__ __forceinline__ void grn_phase(char* smem, const TParams& P, int bid, int tid)
{
  u16 (*As)[136] = reinterpret_cast<u16(*)[136]>(smem);
  u16 (*Bs)[136] = reinterpret_cast<u16(*)[136]>(smem + 8704);
  float (*red_s)[5] = reinterpret_cast<float(*)[5]>(smem + 78336);
  float (*red_q)[5] = reinterpret_cast<float(*)[5]>(smem + 78976);
  float* smean = reinterpret_cast<float*>(smem + 79616);
  float* srstd = reinterpret_cast<float*>(smem + 79744);
  float* hlp   = reinterpret_cast<float*>(smem);          // aliases As (dead)
  float* qv    = reinterpret_cast<float*>(smem + 1024);   // aliases As (dead)

  const int lane = tid & 63, wave = tid >> 6;
  const int q  = lane >> 4, lr = lane & 15;
  const int m0 = bid * 32;
  const bool isqk = ((bid & 31) == 31);

  f32x4 acc[2][4] = {};

  for (int k0 = 0; k0 < DD; k0 += 128) {
#pragma unroll
    for (int p = 0; p < 2; ++p) {
      const int c = tid + p * 256;
      const int row = c >> 4, col = (c & 15) * 8;
      *(uint4*)&As[row][col] = *(const uint4*)(P.eta2 + (size_t)(m0 + row) * DD + k0 + col);
    }
#pragma unroll
    for (int p = 0; p < 16; ++p) {
      const int c = tid + p * 256;
      const int row = c >> 4, col = (c & 15) * 8;
      const float* wp = P.gw + (size_t)row * DD + k0 + col;
      const float4 w0 = *(const float4*)wp, w1 = *(const float4*)(wp + 4);
      *(uint2*)&Bs[row][col]     = pack4(w0.x, w0.y, w0.z, w0.w);
      *(uint2*)&Bs[row][col + 4] = pack4(w1.x, w1.y, w1.z, w1.w);
    }
    __syncthreads();
#pragma unroll
    for (int kk = 0; kk < 4; ++kk) {
      const int koff = kk * 32 + q * 8;
      bf16x8 av[2], bv[4];
#pragma unroll
      for (int i = 0; i < 2; ++i) av[i] = *(const bf16x8*)&As[i * 16 + lr][koff];
#pragma unroll
      for (int j = 0; j < 4; ++j) bv[j] = *(const bf16x8*)&Bs[wave * 64 + j * 16 + lr][koff];
#pragma unroll
      for (int i = 0; i < 2; ++i)
#pragma unroll
        for (int j = 0; j < 4; ++j)
          acc[i][j] = __builtin_amdgcn_mfma_f32_16x16x32_bf16(av[i], bv[j], acc[i][j], 0, 0, 0);
    }
    __syncthreads();
  }

  float pre[2][4][4];
#pragma unroll
  for (int i = 0; i < 2; ++i) {
#pragma unroll
    for (int j = 0; j < 4; ++j) {
      const int n = wave * 64 + j * 16 + lr;
      const float gbn = P.gb[n];
#pragma unroll
      for (int t = 0; t < 4; ++t) {
        const int grow = m0 + i * 16 + q * 4 + t;
        const float gate = acc[i][j][t] + gbn;
        const float sig = 1.f / (1.f + expf(-gate));
        const float e2 = bf2f(P.eta2[(size_t)grow * DD + n]);
        pre[i][j][t] = P.x[(size_t)grow * DD + n] + sig * e2;
      }
    }
  }
#pragma unroll
  for (int i = 0; i < 2; ++i) {
#pragma unroll
    for (int t = 0; t < 4; ++t) {
      float s = 0.f, sq = 0.f;
#pragma unroll
      for (int j = 0; j < 4; ++j) { const float v = pre[i][j][t]; s += v; sq += v * v; }
#pragma unroll
      for (int m = 1; m <= 8; m <<= 1) { s += __shfl_xor(s, m); sq += __shfl_xor(sq, m); }
      if (lr == 0) {
        const int ml = i * 16 + q * 4 + t;
        red_s[ml][wave] = s;
        red_q[ml][wave] = sq;
      }
    }
  }
  __syncthreads();
  if (tid < 32) {
    const float s  = red_s[tid][0] + red_s[tid][1] + red_s[tid][2] + red_s[tid][3];
    const float sq = red_q[tid][0] + red_q[tid][1] + red_q[tid][2] + red_q[tid][3];
    const float mean = s * (1.f / DD);
    const float var = sq * (1.f / DD) - mean * mean;
    smean[tid] = mean;
    srstd[tid] = rsqrtf(var + 1e-5f);
  }
  __syncthreads();
#pragma unroll
  for (int i = 0; i < 2; ++i) {
#pragma unroll
    for (int j = 0; j < 4; ++j) {
      const int n = wave * 64 + j * 16 + lr;
      const float gn = P.lng[n], bn = P.lnb[n];
#pragma unroll
      for (int t = 0; t < 4; ++t) {
        const int ml = i * 16 + q * 4 + t;
        const int grow = m0 + ml;
        const float hn = (pre[i][j][t] - smean[ml]) * srstd[ml] * gn + bn;
        P.hbuf[(size_t)grow * DD + n] = f2bf(hn);
        if (isqk && ml == 31) {
          P.hlast[(size_t)(grow >> 10) * DD + n] = hn;
          hlp[n] = hn;
        }
      }
    }
  }

  if (isqk) {
    __syncthreads();
    const int b = bid >> 5;
    // q[r] = hlp . wq[r], 4 threads/row
    {
      const int j = tid >> 2, seg = tid & 3;
      const float* sp = hlp + seg * 64;
#pragma unroll
      for (int pass = 0; pass < 4; ++pass) {
        const int r = pass * 64 + j;
        const float* wr_ = P.wq + (size_t)r * DD + seg * 64;
        float acc2 = 0.f;
#pragma unroll
        for (int k = 0; k < 64; k += 4) {
          const float4 w4 = *(const float4*)(wr_ + k);
          acc2 += w4.x * sp[k] + w4.y * sp[k + 1] + w4.z * sp[k + 2] + w4.w * sp[k + 3];
        }
        acc2 += __shfl_xor(acc2, 1);
        acc2 += __shfl_xor(acc2, 2);
        if (seg == 0) qv[r] = acc2;
      }
    }
    __syncthreads();
#pragma unroll
    for (int h = 0; h < NH; ++h) {
      float acc2 = 0.f;
      const float* wkb = P.wk + (size_t)(h * DKH) * DD + tid;
#pragma unroll 8
      for (int d = 0; d < DKH; ++d)
        acc2 += qv[h * DKH + d] * wkb[(size_t)d * DD];
      P.qkbuf[((size_t)b * NH + h) * DD + tid] = acc2 * 0.125f;
    }
  }
}

// ============================ phase: tail-weight cast ======================
__device__ __forceinline__ void wcast_phase(const TParams& P, int cb, int tid)
{
  const int base = cb * 1280;
#pragma unroll
  for (int r = 0; r < 5; ++r) {
    const int e = base + r * 256 + tid;
    const int mi = e >> 16, off = e & 65535;
    const float* s = (mi == 0) ? P.wow : (mi == 1) ? P.g2f1w : (mi == 2) ? P.g2f2w
                   : (mi == 3) ? P.g2gw : P.wv;
    P.wbf[e] = f2bf(s[off]);
  }
}

// ============================ phase: attention partials ====================
// bid in [0,256): chunk=bid&31, b=bid>>5. smem >= 21504 B.
__device__ __forceinline__ void attn_phase(char* smem, const TParams& P, int bid, int tid)
{
  float (*qk4)[DD] = reinterpret_cast<float(*)[DD]>(smem);
  u16 (*hch)[264]  = reinterpret_cast<u16(*)[264]>(smem + 4096);
  float (*E)[NH]   = reinterpret_cast<float(*)[NH]>(smem + 20992);
  const int chunk = bid & 31, b = bid >> 5;

#pragma unroll
  for (int h = 0; h < NH; ++h)
    qk4[h][tid] = P.qkbuf[((size_t)b * NH + h) * DD + tid];
#pragma unroll
  for (int p = 0; p < 4; ++p) {
    const int idx = p * 256 + tid;
    const int row = idx >> 5, col = (idx & 31) * 8;
    *(uint4*)&hch[row][col] =
        *(const uint4*)(P.hbuf + ((size_t)(b * TT + chunk * SROWS + row)) * DD + col);
  }
  __syncthreads();

  {
    const int s = tid >> 3, sub = tid & 7;
    const u16* hp = &hch[s][sub * 32];
    float part[NH] = {};
#pragma unroll
    for (int v = 0; v < 4; ++v) {
      const bf16x8 h8 = *(const bf16x8*)(hp + v * 8);
      float hf[8];
#pragma unroll
      for (int e = 0; e < 8; ++e) hf[e] = bf2f((u16)h8[e]);
#pragma unroll
      for (int h = 0; h < NH; ++h) {
        const float* qp = &qk4[h][sub * 32 + v * 8];
#pragma unroll
        for (int e = 0; e < 8; ++e) part[h] += hf[e] * qp[e];
      }
    }
#pragma unroll
    for (int h = 0; h < NH; ++h) {
      float p = part[h];
      p += __shfl_xor(p, 1);
      p += __shfl_xor(p, 2);
      p += __shfl_xor(p, 4);
      if (sub == 0) E[s][h] = __expf(fminf(fmaxf(p, -30.f), 30.f));
    }
  }
  __syncthreads();

  {
    float eh[NH] = {};
    for (int s = 0; s < SROWS; ++s) {
      const float hv = bf2f(hch[s][tid]);
      const float4 E4 = *(const float4*)&E[s][0];
      eh[0] += E4.x * hv; eh[1] += E4.y * hv;
      eh[2] += E4.z * hv; eh[3] += E4.w * hv;
    }
    const size_t pb = ((size_t)(b * SPLIT + chunk)) * NH * DD;
#pragma unroll
    for (int h = 0; h < NH; ++h) P.p_eh[pb + h * DD + tid] = eh[h];
  }
  if (tid < NH) {
    float s = 0.f;
    for (int s2 = 0; s2 < SROWS; ++s2) s += E[s2][tid];
    P.p_den[(b * SPLIT + chunk) * NH + tid] = s;
  }
}

// ============================ phase: tail (256 threads) ====================
__device__ __forceinline__ void mv4w(const u16* __restrict__ W16,
                                     const float* __restrict__ srcbuf,
                                     float* __restrict__ dst,
                                     int wave, int lane)
{
  const int half = lane >> 5, l32 = lane & 31;
  float s[8];
  {
    const float4 s0 = *(const float4*)(srcbuf + l32 * 8);
    const float4 s1 = *(const float4*)(srcbuf + l32 * 8 + 4);
    s[0] = s0.x; s[1] = s0.y; s[2] = s0.z; s[3] = s0.w;
    s[4] = s1.x; s[5] = s1.y; s[6] = s1.z; s[7] = s1.w;
  }
#pragma unroll 4
  for (int i = 0; i < 32; ++i) {
    const int r = wave * 64 + i * 2 + half;
    const bf16x8 wv = *(const bf16x8*)(W16 + (size_t)r * DD + l32 * 8);
    float acc = 0.f;
#pragma unroll
    for (int e = 0; e < 8; ++e) acc += bf2f((u16)wv[e]) * s[e];
#pragma unroll
    for (int off = 16; off; off >>= 1) acc += __shfl_xor(acc, off);
    if (l32 == 0) dst[r] = acc;
  }
}

#define LN256(val, gam, bet, dst) \
  __syncthreads(); \
  lnS[tid] = (val); lnQ[tid] = (val) * (val); \
  __syncthreads(); \
  if (tid < 64) { \
    float s_ = 0.f, q_ = 0.f; \
    _Pragma("unroll") \
    for (int i_ = 0; i_ < 4; ++i_) { s_ += lnS[tid + 64 * i_]; q_ += lnQ[tid + 64 * i_]; } \
    s_ = wred(s_); q_ = wred(q_); \
    if (tid == 0) { const float m_ = s_ * (1.f / DD); red2[0] = m_; red2[1] = rsqrtf(q_ * (1.f / DD) - m_ * m_ + 1e-5f); } \
  } \
  __syncthreads(); \
  dst[tid] = ((val) - red2[0]) * red2[1] * gam[tid] + bet[tid]; \
  __syncthreads();

__device__ __forceinline__ void tail_phase(char* smem, const TParams& P, int b, int tid)
{
  float* pv    = reinterpret_cast<float*>(smem);          // 1024 f
  float* den   = reinterpret_cast<float*>(smem + 4096);   // 4 f
  float* hl    = reinterpret_cast<float*>(smem + 4112);
  float* bufA  = reinterpret_cast<float*>(smem + 5136);
  float* bufB  = reinterpret_cast<float*>(smem + 6160);
  float* bufC  = reinterpret_cast<float*>(smem + 7184);
  float* part0 = reinterpret_cast<float*>(smem + 8208);
  float* lnS   = reinterpret_cast<float*>(smem + 9232);
  float* lnQ   = reinterpret_cast<float*>(smem + 10256);
  float* red2  = reinterpret_cast<float*>(smem + 11280);
  const int wave = tid >> 6, lane = tid & 63;
  const int half = lane >> 5, l32 = lane & 31;

  float pvr[4];
#pragma unroll
  for (int k = 0; k < 4; ++k) {
    float s = 0.f;
    for (int c = 0; c < SPLIT; ++c)
      s += P.p_eh[((size_t)(b * SPLIT + c)) * NH * DD + k * 256 + tid];
    pvr[k] = s;
  }
  if (tid < NH) {
    float s = 0.f;
    for (int c = 0; c < SPLIT; ++c) s += P.p_den[(b * SPLIT + c) * NH + tid];
    den[tid] = s;
  }
  hl[tid] = P.hlast[(size_t)b * DD + tid];
  __syncthreads();
#pragma unroll
  for (int k = 0; k < 4; ++k) pv[k * 256 + tid] = pvr[k] / den[k];
  __syncthreads();

  // ctx = (eh/den) @ wv^T -> bufB
  {
    const u16* wv16 = P.wbf + 4 * 65536;
#pragma unroll 4
    for (int i = 0; i < 32; ++i) {
      const int r = wave * 64 + i * 2 + half;
      const float* sp = pv + (r >> 6) * DD + l32 * 8;
      const float4 s0 = *(const float4*)sp;
      const float4 s1 = *(const float4*)(sp + 4);
      const bf16x8 wvv = *(const bf16x8*)(wv16 + (size_t)r * DD + l32 * 8);
      float acc = bf2f((u16)wvv[0]) * s0.x + bf2f((u16)wvv[1]) * s0.y
                + bf2f((u16)wvv[2]) * s0.z + bf2f((u16)wvv[3]) * s0.w
                + bf2f((u16)wvv[4]) * s1.x + bf2f((u16)wvv[5]) * s1.y
                + bf2f((u16)wvv[6]) * s1.z + bf2f((u16)wvv[7]) * s1.w;
#pragma unroll
      for (int off = 16; off; off >>= 1) acc += __shfl_xor(acc, off);
      if (l32 == 0) bufB[r] = acc;
    }
  }
  __syncthreads();

  mv4w(P.wbf + 0 * 65536, bufB, part0, wave, lane);
  __syncthreads();
  float v = hl[tid] + part0[tid] + P.wob[tid];
  LN256(v, P.alng, P.alnb, bufA)

  mv4w(P.wbf + 1 * 65536, bufA, part0, wave, lane);
  __syncthreads();
  {
    const float e1 = part0[tid] + P.g2f1b[tid];
    bufB[tid] = e1 > 0.f ? e1 : expm1f(e1);
  }
  __syncthreads();

  mv4w(P.wbf + 2 * 65536, bufB, part0, wave, lane);
  __syncthreads();
  bufC[tid] = part0[tid] + P.g2f2b[tid];
  __syncthreads();

  mv4w(P.wbf + 3 * 65536, bufC, part0, wave, lane);
  __syncthreads();
  {
    const float g = part0[tid] + P.g2gb[tid];
    v = bufA[tid] + (1.f / (1.f + expf(-g))) * bufC[tid];
  }
  LN256(v, P.g2lng, P.g2lnb, bufA)

  if (tid < 64 * NQ) {
    const int qi = tid >> 6, l = tid & 63;
    float acc = 0.f;
#pragma unroll
    for (int i = 0; i < 4; ++i) acc += P.qhw[(size_t)qi * DD + l + 64 * i] * bufA[l + 64 * i];
    acc = wred(acc);
    if (l == 0) P.out[b * NQ + qi] = acc + P.qhb[qi];
  }
}

// ============================ cooperative mega-kernel ======================
__global__ __launch_bounds__(256, 2) void tft_all(TParams P)
{
  cg::grid_group grid = cg::this_grid();
  __shared__ __align__(16) char smem[79872];
  const int bid = blockIdx.x, tid = threadIdx.x;

  gemm_phase<false, 1>(smem, (const void*)P.x,    P.f1w, P.f1b, P.eta1, bid, tid);
  grid.sync();
  gemm_phase<true,  0>(smem, (const void*)P.eta1, P.f2w, P.f2b, P.eta2, bid, tid);
  grid.sync();
  if (bid < 256) grn_phase(smem, P, bid, tid);
  else           wcast_phase(P, bid - 256, tid);
  grid.sync();
  if (bid < 256) attn_phase(smem, P, bid, tid);
  grid.sync();
  if (bid < BB)  tail_phase(smem, P, bid, tid);
}

// ============================ fallback kernels =============================
__global__ __launch_bounds__(256) void k_gemm1(TParams P) {
  __shared__ __align__(16) char smem[67584];
  gemm_phase<false, 1>(smem, (const void*)P.x, P.f1w, P.f1b, P.eta1, blockIdx.x, threadIdx.x);
}
__global__ __launch_bounds__(256) void k_gemm2(TParams P) {
  __shared__ __align__(16) char smem[67584];
  gemm_phase<true, 0>(smem, (const void*)P.eta1, P.f2w, P.f2b, P.eta2, blockIdx.x, threadIdx.x);
}
__global__ __launch_bounds__(256) void k_grn(TParams P) {
  __shared__ __align__(16) char smem[79872];
  grn_phase(smem, P, blockIdx.x, threadIdx.x);
}
__global__ __launch_bounds__(256) void k_wcast(TParams P) {
  wcast_phase(P, blockIdx.x, threadIdx.x);
}
__global__ __launch_bounds__(256) void k_attn(TParams P) {
  __shared__ __align__(16) char smem[21504];
  attn_phase(smem, P, blockIdx.x, threadIdx.x);
}
__global__ __launch_bounds__(256) void k_tail(TParams P) {
  __shared__ __align__(16) char smem[11296];
  tail_phase(smem, P, blockIdx.x, threadIdx.x);
}

// ---------------------------------------------------------------------------
extern "C" void kernel_launch(void* const* d_in, const int* in_sizes, int n_in,
                              void* d_out, int out_size, void* d_ws, size_t ws_size,
                              hipStream_t stream)
{
  char* w8 = (char*)d_ws;
  TParams P;
  P.x     = (const float*)d_in[0];
  P.f1w   = (const float*)d_in[1];  P.f1b = (const float*)d_in[2];
  P.f2w   = (const float*)d_in[3];  P.f2b = (const float*)d_in[4];
  P.gw    = (const float*)d_in[5];  P.gb  = (const float*)d_in[6];
  P.lng   = (const float*)d_in[7];  P.lnb = (const float*)d_in[8];
  P.wq    = (const float*)d_in[9];
  P.wk    = (const float*)d_in[10];
  P.wv    = (const float*)d_in[11];
  P.wow   = (const float*)d_in[12]; P.wob = (const float*)d_in[13];
  P.alng  = (const float*)d_in[14]; P.alnb = (const float*)d_in[15];
  P.g2f1w = (const float*)d_in[16]; P.g2f1b = (const float*)d_in[17];
  P.g2f2w = (const float*)d_in[18]; P.g2f2b = (const float*)d_in[19];
  P.g2gw  = (const float*)d_in[20]; P.g2gb  = (const float*)d_in[21];
  P.g2lng = (const float*)d_in[22]; P.g2lnb = (const float*)d_in[23];
  P.qhw   = (const float*)d_in[24]; P.qhb   = (const float*)d_in[25];
  P.out   = (float*)d_out;

  P.wbf   = (u16*)(w8);                            // 5*128 KB bf16 tail weights
  P.p_eh  = (float*)(w8 + ((size_t)1 << 20));      // 1 MB
  P.p_den = (float*)(w8 + ((size_t)2100 << 10));   // 4 KB
  P.qkbuf = (float*)(w8 + ((size_t)2200 << 10));   // 8 KB
  P.eta1  = (u16*)(w8 + ((size_t)4  << 20));       // 4 MB
  P.eta2  = (u16*)(w8 + ((size_t)8  << 20));       // 4 MB
  P.hbuf  = (u16*)(w8 + ((size_t)12 << 20));       // 4 MB
  P.hlast = (float*)(w8 + ((size_t)16 << 20));     // 8 KB

  void* args[] = { &P };
  hipError_t err = hipLaunchCooperativeKernel((const void*)tft_all, dim3(512), dim3(256),
                                              args, 0, stream);
  if (err != hipSuccess) {
    // deterministic fallback: same phases as 6 regular launches
    k_gemm1<<<dim3(512), dim3(256), 0, stream>>>(P);
    k_gemm2<<<dim3(512), dim3(256), 0, stream>>>(P);
    k_grn  <<<dim3(256), dim3(256), 0, stream>>>(P);
    k_wcast<<<dim3(256), dim3(256), 0, stream>>>(P);
    k_attn <<<dim3(256), dim3(256), 0, stream>>>(P);
    k_tail <<<dim3(BB),  dim3(256), 0, stream>>>(P);
  }
}

// Round 11
// 135.297 us; speedup vs baseline: 2.6266x; 2.6266x over previous
//
#include <hip/hip_runtime.h>
#include <hip/hip_bf16.h>
#include <math.h>

#define DD 256
#define BB 8
#define TT 1024
#define MM (BB*TT)
#define NH 4
#define DKH 64
#define NQ 3
#define SPLIT 32
#define SROWS (TT/SPLIT)   // 32

typedef __attribute__((ext_vector_type(8))) short bf16x8;
typedef __attribute__((ext_vector_type(4))) float f32x4;
typedef unsigned short u16;
typedef unsigned int u32;

__device__ __forceinline__ float bf2f(u16 u) {
  return __uint_as_float(((u32)u) << 16);
}
__device__ __forceinline__ u16 f2bf(float x) {
  __hip_bfloat16 h = __float2bfloat16(x);
  return *reinterpret_cast<u16*>(&h);
}
__device__ __forceinline__ uint2 pack4(float a, float b, float c, float d) {
  uint2 r;
  r.x = (u32)f2bf(a) | ((u32)f2bf(b) << 16);
  r.y = (u32)f2bf(c) | ((u32)f2bf(d) << 16);
  return r;
}
__device__ __forceinline__ float wred(float v) {
#pragma unroll
  for (int off = 32; off; off >>= 1) v += __shfl_xor(v, off);
  return v;
}

struct TParams {
  const float* x;
  const float* f1w; const float* f1b;
  const float* f2w; const float* f2b;
  const float* gw;  const float* gb;
  const float* lng; const float* lnb;
  const float* wq;  const float* wk;  const float* wv;
  const float* wow; const float* wob;
  const float* alng; const float* alnb;
  const float* g2f1w; const float* g2f1b;
  const float* g2f2w; const float* g2f2b;
  const float* g2gw;  const float* g2gb;
  const float* g2lng; const float* g2lnb;
  const float* qhw;   const float* qhb;
  u16* eta1; u16* eta2; u16* hbuf; float* hlast;
  float* qkbuf; u16* wbf; float* p_eh; float* p_den;
  float* out;
};

// ============================ phase: 64x64 GEMM ============================
// bid in [0,512): m0=(bid>>2)*64, n0=(bid&3)*64. smem >= 67584 B.
template<bool ABF, int ACT>
__device__ __forceinline__ void gemm_phase(char* smem, const void* A_,
                                           const float* W, const float* bias,
                                           u16* out, int bid, int tid)
{
  u16 (*As)[264] = reinterpret_cast<u16(*)[264]>(smem);
  u16 (*Bs)[264] = reinterpret_cast<u16(*)[264]>(smem + 33792);
  const int lane = tid & 63, wave = tid >> 6;
  const int wr = wave >> 1, wc = wave & 1;
  const int q  = lane >> 4, lr = lane & 15;
  const int m0 = (bid >> 2) * 64, n0 = (bid & 3) * 64;

#pragma unroll
  for (int p = 0; p < 8; ++p) {
    const int c = tid + p * 256;
    const int row = c >> 5, col = (c & 31) * 8;
    if constexpr (ABF) {
      *(uint4*)&As[row][col] = *(const uint4*)((const u16*)A_ + (size_t)(m0 + row) * DD + col);
    } else {
      const float* ap = (const float*)A_ + (size_t)(m0 + row) * DD + col;
      const float4 v0 = *(const float4*)ap, v1 = *(const float4*)(ap + 4);
      *(uint2*)&As[row][col]     = pack4(v0.x, v0.y, v0.z, v0.w);
      *(uint2*)&As[row][col + 4] = pack4(v1.x, v1.y, v1.z, v1.w);
    }
    const float* wp = W + (size_t)(n0 + row) * DD + col;
    const float4 w0 = *(const float4*)wp, w1 = *(const float4*)(wp + 4);
    *(uint2*)&Bs[row][col]     = pack4(w0.x, w0.y, w0.z, w0.w);
    *(uint2*)&Bs[row][col + 4] = pack4(w1.x, w1.y, w1.z, w1.w);
  }
  __syncthreads();

  f32x4 acc[2][2] = {};
#pragma unroll
  for (int kk = 0; kk < 8; ++kk) {
    const int koff = kk * 32 + q * 8;
    bf16x8 av[2], bv[2];
    av[0] = *(const bf16x8*)&As[wr * 32 + lr][koff];
    av[1] = *(const bf16x8*)&As[wr * 32 + 16 + lr][koff];
    bv[0] = *(const bf16x8*)&Bs[wc * 32 + lr][koff];
    bv[1] = *(const bf16x8*)&Bs[wc * 32 + 16 + lr][koff];
#pragma unroll
    for (int i = 0; i < 2; ++i)
#pragma unroll
      for (int j = 0; j < 2; ++j)
        acc[i][j] = __builtin_amdgcn_mfma_f32_16x16x32_bf16(av[i], bv[j], acc[i][j], 0, 0, 0);
  }

#pragma unroll
  for (int i = 0; i < 2; ++i) {
#pragma unroll
    for (int j = 0; j < 2; ++j) {
      const int col = n0 + wc * 32 + j * 16 + lr;
      const float bvv = bias ? bias[col] : 0.f;
#pragma unroll
      for (int t = 0; t < 4; ++t) {
        const int row = m0 + wr * 32 + i * 16 + q * 4 + t;
        float v = acc[i][j][t] + bvv;
        if (ACT == 1) v = v > 0.f ? v : expm1f(v);
        out[(size_t)row * DD + col] = f2bf(v);
      }
    }
  }
}

// ============================ phase: GRN gate+LN (+qk) =====================
// bid in [0,256): 32 rows each. smem >= 79872 B. Last block of each batch
// also computes qkbuf for that batch (fused qk_prep).
__device__ __forceinline__ void grn_phase(char* smem, const TParams& P, int bid, int tid)
{
  u16 (*As)[136] = reinterpret_cast<u16(*)[136]>(smem);
  u16 (*Bs)[136] = reinterpret_cast<u16(*)[136]>(smem + 8704);
  float (*red_s)[5] = reinterpret_cast<float(*)[5]>(smem + 78336);
  float (*red_q)[5] = reinterpret_cast<float(*)[5]>(smem + 78976);
  float* smean = reinterpret_cast<float*>(smem + 79616);
  float* srstd = reinterpret_cast<float*>(smem + 79744);
  float* hlp   = reinterpret_cast<float*>(smem);          // aliases As (dead after loop)
  float* qv    = reinterpret_cast<float*>(smem + 1024);   // aliases As (dead after loop)

  const int lane = tid & 63, wave = tid >> 6;
  const int q  = lane >> 4, lr = lane & 15;
  const int m0 = bid * 32;
  const bool isqk = ((bid & 31) == 31);

  f32x4 acc[2][4] = {};

  for (int k0 = 0; k0 < DD; k0 += 128) {
#pragma unroll
    for (int p = 0; p < 2; ++p) {
      const int c = tid + p * 256;
      const int row = c >> 4, col = (c & 15) * 8;
      *(uint4*)&As[row][col] = *(const uint4*)(P.eta2 + (size_t)(m0 + row) * DD + k0 + col);
    }
#pragma unroll
    for (int p = 0; p < 16; ++p) {
      const int c = tid + p * 256;
      const int row = c >> 4, col = (c & 15) * 8;
      const float* wp = P.gw + (size_t)row * DD + k0 + col;
      const float4 w0 = *(const float4*)wp, w1 = *(const float4*)(wp + 4);
      *(uint2*)&Bs[row][col]     = pack4(w0.x, w0.y, w0.z, w0.w);
      *(uint2*)&Bs[row][col + 4] = pack4(w1.x, w1.y, w1.z, w1.w);
    }
    __syncthreads();
#pragma unroll
    for (int kk = 0; kk < 4; ++kk) {
      const int koff = kk * 32 + q * 8;
      bf16x8 av[2], bv[4];
#pragma unroll
      for (int i = 0; i < 2; ++i) av[i] = *(const bf16x8*)&As[i * 16 + lr][koff];
#pragma unroll
      for (int j = 0; j < 4; ++j) bv[j] = *(const bf16x8*)&Bs[wave * 64 + j * 16 + lr][koff];
#pragma unroll
      for (int i = 0; i < 2; ++i)
#pragma unroll
        for (int j = 0; j < 4; ++j)
          acc[i][j] = __builtin_amdgcn_mfma_f32_16x16x32_bf16(av[i], bv[j], acc[i][j], 0, 0, 0);
    }
    __syncthreads();
  }

  float pre[2][4][4];
#pragma unroll
  for (int i = 0; i < 2; ++i) {
#pragma unroll
    for (int j = 0; j < 4; ++j) {
      const int n = wave * 64 + j * 16 + lr;
      const float gbn = P.gb[n];
#pragma unroll
      for (int t = 0; t < 4; ++t) {
        const int grow = m0 + i * 16 + q * 4 + t;
        const float gate = acc[i][j][t] + gbn;
        const float sig = 1.f / (1.f + expf(-gate));
        const float e2 = bf2f(P.eta2[(size_t)grow * DD + n]);
        pre[i][j][t] = P.x[(size_t)grow * DD + n] + sig * e2;
      }
    }
  }
#pragma unroll
  for (int i = 0; i < 2; ++i) {
#pragma unroll
    for (int t = 0; t < 4; ++t) {
      float s = 0.f, sq = 0.f;
#pragma unroll
      for (int j = 0; j < 4; ++j) { const float v = pre[i][j][t]; s += v; sq += v * v; }
#pragma unroll
      for (int m = 1; m <= 8; m <<= 1) { s += __shfl_xor(s, m); sq += __shfl_xor(sq, m); }
      if (lr == 0) {
        const int ml = i * 16 + q * 4 + t;
        red_s[ml][wave] = s;
        red_q[ml][wave] = sq;
      }
    }
  }
  __syncthreads();
  if (tid < 32) {
    const float s  = red_s[tid][0] + red_s[tid][1] + red_s[tid][2] + red_s[tid][3];
    const float sq = red_q[tid][0] + red_q[tid][1] + red_q[tid][2] + red_q[tid][3];
    const float mean = s * (1.f / DD);
    const float var = sq * (1.f / DD) - mean * mean;
    smean[tid] = mean;
    srstd[tid] = rsqrtf(var + 1e-5f);
  }
  __syncthreads();
#pragma unroll
  for (int i = 0; i < 2; ++i) {
#pragma unroll
    for (int j = 0; j < 4; ++j) {
      const int n = wave * 64 + j * 16 + lr;
      const float gn = P.lng[n], bn = P.lnb[n];
#pragma unroll
      for (int t = 0; t < 4; ++t) {
        const int ml = i * 16 + q * 4 + t;
        const int grow = m0 + ml;
        const float hn = (pre[i][j][t] - smean[ml]) * srstd[ml] * gn + bn;
        P.hbuf[(size_t)grow * DD + n] = f2bf(hn);
        if (isqk && ml == 31) {
          P.hlast[(size_t)(grow >> 10) * DD + n] = hn;
          hlp[n] = hn;
        }
      }
    }
  }

  if (isqk) {
    __syncthreads();
    const int b = bid >> 5;
    // q[r] = hlp . wq[r], 4 threads/row
    {
      const int j = tid >> 2, seg = tid & 3;
      const float* sp = hlp + seg * 64;
#pragma unroll
      for (int pass = 0; pass < 4; ++pass) {
        const int r = pass * 64 + j;
        const float* wr_ = P.wq + (size_t)r * DD + seg * 64;
        float acc2 = 0.f;
#pragma unroll
        for (int k = 0; k < 64; k += 4) {
          const float4 w4 = *(const float4*)(wr_ + k);
          acc2 += w4.x * sp[k] + w4.y * sp[k + 1] + w4.z * sp[k + 2] + w4.w * sp[k + 3];
        }
        acc2 += __shfl_xor(acc2, 1);
        acc2 += __shfl_xor(acc2, 2);
        if (seg == 0) qv[r] = acc2;
      }
    }
    __syncthreads();
#pragma unroll
    for (int h = 0; h < NH; ++h) {
      float acc2 = 0.f;
      const float* wkb = P.wk + (size_t)(h * DKH) * DD + tid;
#pragma unroll 8
      for (int d = 0; d < DKH; ++d)
        acc2 += qv[h * DKH + d] * wkb[(size_t)d * DD];
      P.qkbuf[((size_t)b * NH + h) * DD + tid] = acc2 * 0.125f;
    }
  }
}

// ============================ phase: tail-weight cast ======================
// cb in [0,512): 640 elems each (5 matrices * 65536 / 512).
__device__ __forceinline__ void wcast_phase(const TParams& P, int cb, int tid)
{
  const int base = cb * 640;
#pragma unroll
  for (int r = 0; r < 3; ++r) {
    const int k = r * 256 + tid;
    if (k < 640) {
      const int e = base + k;
      const int mi = e >> 16, off = e & 65535;
      const float* s = (mi == 0) ? P.wow : (mi == 1) ? P.g2f1w : (mi == 2) ? P.g2f2w
                     : (mi == 3) ? P.g2gw : P.wv;
      P.wbf[e] = f2bf(s[off]);
    }
  }
}

// ============================ phase: attention partials ====================
// bid in [0,256): chunk=bid&31, b=bid>>5. smem >= 21504 B.
__device__ __forceinline__ void attn_phase(char* smem, const TParams& P, int bid, int tid)
{
  float (*qk4)[DD] = reinterpret_cast<float(*)[DD]>(smem);
  u16 (*hch)[264]  = reinterpret_cast<u16(*)[264]>(smem + 4096);
  float (*E)[NH]   = reinterpret_cast<float(*)[NH]>(smem + 20992);
  const int chunk = bid & 31, b = bid >> 5;

#pragma unroll
  for (int h = 0; h < NH; ++h)
    qk4[h][tid] = P.qkbuf[((size_t)b * NH + h) * DD + tid];
#pragma unroll
  for (int p = 0; p < 4; ++p) {
    const int idx = p * 256 + tid;
    const int row = idx >> 5, col = (idx & 31) * 8;
    *(uint4*)&hch[row][col] =
        *(const uint4*)(P.hbuf + ((size_t)(b * TT + chunk * SROWS + row)) * DD + col);
  }
  __syncthreads();

  {
    const int s = tid >> 3, sub = tid & 7;
    const u16* hp = &hch[s][sub * 32];
    float part[NH] = {};
#pragma unroll
    for (int v = 0; v < 4; ++v) {
      const bf16x8 h8 = *(const bf16x8*)(hp + v * 8);
      float hf[8];
#pragma unroll
      for (int e = 0; e < 8; ++e) hf[e] = bf2f((u16)h8[e]);
#pragma unroll
      for (int h = 0; h < NH; ++h) {
        const float* qp = &qk4[h][sub * 32 + v * 8];
#pragma unroll
        for (int e = 0; e < 8; ++e) part[h] += hf[e] * qp[e];
      }
    }
#pragma unroll
    for (int h = 0; h < NH; ++h) {
      float p = part[h];
      p += __shfl_xor(p, 1);
      p += __shfl_xor(p, 2);
      p += __shfl_xor(p, 4);
      if (sub == 0) E[s][h] = __expf(fminf(fmaxf(p, -30.f), 30.f));
    }
  }
  __syncthreads();

  {
    float eh[NH] = {};
    for (int s = 0; s < SROWS; ++s) {
      const float hv = bf2f(hch[s][tid]);
      const float4 E4 = *(const float4*)&E[s][0];
      eh[0] += E4.x * hv; eh[1] += E4.y * hv;
      eh[2] += E4.z * hv; eh[3] += E4.w * hv;
    }
    const size_t pb = ((size_t)(b * SPLIT + chunk)) * NH * DD;
#pragma unroll
    for (int h = 0; h < NH; ++h) P.p_eh[pb + h * DD + tid] = eh[h];
  }
  if (tid < NH) {
    float s = 0.f;
    for (int s2 = 0; s2 < SROWS; ++s2) s += E[s2][tid];
    P.p_den[(b * SPLIT + chunk) * NH + tid] = s;
  }
}

// ============================ phase: tail (256 threads) ====================
__device__ __forceinline__ void mv4w(const u16* __restrict__ W16,
                                     const float* __restrict__ srcbuf,
                                     float* __restrict__ dst,
                                     int wave, int lane)
{
  const int half = lane >> 5, l32 = lane & 31;
  float s[8];
  {
    const float4 s0 = *(const float4*)(srcbuf + l32 * 8);
    const float4 s1 = *(const float4*)(srcbuf + l32 * 8 + 4);
    s[0] = s0.x; s[1] = s0.y; s[2] = s0.z; s[3] = s0.w;
    s[4] = s1.x; s[5] = s1.y; s[6] = s1.z; s[7] = s1.w;
  }
#pragma unroll 4
  for (int i = 0; i < 32; ++i) {
    const int r = wave * 64 + i * 2 + half;
    const bf16x8 wv = *(const bf16x8*)(W16 + (size_t)r * DD + l32 * 8);
    float acc = 0.f;
#pragma unroll
    for (int e = 0; e < 8; ++e) acc += bf2f((u16)wv[e]) * s[e];
#pragma unroll
    for (int off = 16; off; off >>= 1) acc += __shfl_xor(acc, off);
    if (l32 == 0) dst[r] = acc;
  }
}

#define LN256(val, gam, bet, dst) \
  __syncthreads(); \
  lnS[tid] = (val); lnQ[tid] = (val) * (val); \
  __syncthreads(); \
  if (tid < 64) { \
    float s_ = 0.f, q_ = 0.f; \
    _Pragma("unroll") \
    for (int i_ = 0; i_ < 4; ++i_) { s_ += lnS[tid + 64 * i_]; q_ += lnQ[tid + 64 * i_]; } \
    s_ = wred(s_); q_ = wred(q_); \
    if (tid == 0) { const float m_ = s_ * (1.f / DD); red2[0] = m_; red2[1] = rsqrtf(q_ * (1.f / DD) - m_ * m_ + 1e-5f); } \
  } \
  __syncthreads(); \
  dst[tid] = ((val) - red2[0]) * red2[1] * gam[tid] + bet[tid]; \
  __syncthreads();

__device__ __forceinline__ void tail_phase(char* smem, const TParams& P, int b, int tid)
{
  float* pv    = reinterpret_cast<float*>(smem);          // 1024 f
  float* den   = reinterpret_cast<float*>(smem + 4096);   // 4 f
  float* hl    = reinterpret_cast<float*>(smem + 4112);
  float* bufA  = reinterpret_cast<float*>(smem + 5136);
  float* bufB  = reinterpret_cast<float*>(smem + 6160);
  float* bufC  = reinterpret_cast<float*>(smem + 7184);
  float* part0 = reinterpret_cast<float*>(smem + 8208);
  float* lnS   = reinterpret_cast<float*>(smem + 9232);
  float* lnQ   = reinterpret_cast<float*>(smem + 10256);
  float* red2  = reinterpret_cast<float*>(smem + 11280);
  const int wave = tid >> 6, lane = tid & 63;
  const int half = lane >> 5, l32 = lane & 31;

  float pvr[4];
#pragma unroll
  for (int k = 0; k < 4; ++k) {
    float s = 0.f;
    for (int c = 0; c < SPLIT; ++c)
      s += P.p_eh[((size_t)(b * SPLIT + c)) * NH * DD + k * 256 + tid];
    pvr[k] = s;
  }
  if (tid < NH) {
    float s = 0.f;
    for (int c = 0; c < SPLIT; ++c) s += P.p_den[(b * SPLIT + c) * NH + tid];
    den[tid] = s;
  }
  hl[tid] = P.hlast[(size_t)b * DD + tid];
  __syncthreads();
#pragma unroll
  for (int k = 0; k < 4; ++k) pv[k * 256 + tid] = pvr[k] / den[k];
  __syncthreads();

  // ctx = (eh/den) @ wv^T -> bufB
  {
    const u16* wv16 = P.wbf + 4 * 65536;
#pragma unroll 4
    for (int i = 0; i < 32; ++i) {
      const int r = wave * 64 + i * 2 + half;
      const float* sp = pv + (r >> 6) * DD + l32 * 8;
      const float4 s0 = *(const float4*)sp;
      const float4 s1 = *(const float4*)(sp + 4);
      const bf16x8 wvv = *(const bf16x8*)(wv16 + (size_t)r * DD + l32 * 8);
      float acc = bf2f((u16)wvv[0]) * s0.x + bf2f((u16)wvv[1]) * s0.y
                + bf2f((u16)wvv[2]) * s0.z + bf2f((u16)wvv[3]) * s0.w
                + bf2f((u16)wvv[4]) * s1.x + bf2f((u16)wvv[5]) * s1.y
                + bf2f((u16)wvv[6]) * s1.z + bf2f((u16)wvv[7]) * s1.w;
#pragma unroll
      for (int off = 16; off; off >>= 1) acc += __shfl_xor(acc, off);
      if (l32 == 0) bufB[r] = acc;
    }
  }
  __syncthreads();

  mv4w(P.wbf + 0 * 65536, bufB, part0, wave, lane);
  __syncthreads();
  float v = hl[tid] + part0[tid] + P.wob[tid];
  LN256(v, P.alng, P.alnb, bufA)

  mv4w(P.wbf + 1 * 65536, bufA, part0, wave, lane);
  __syncthreads();
  {
    const float e1 = part0[tid] + P.g2f1b[tid];
    bufB[tid] = e1 > 0.f ? e1 : expm1f(e1);
  }
  __syncthreads();

  mv4w(P.wbf + 2 * 65536, bufB, part0, wave, lane);
  __syncthreads();
  bufC[tid] = part0[tid] + P.g2f2b[tid];
  __syncthreads();

  mv4w(P.wbf + 3 * 65536, bufC, part0, wave, lane);
  __syncthreads();
  {
    const float g = part0[tid] + P.g2gb[tid];
    v = bufA[tid] + (1.f / (1.f + expf(-g))) * bufC[tid];
  }
  LN256(v, P.g2lng, P.g2lnb, bufA)

  if (tid < 64 * NQ) {
    const int qi = tid >> 6, l = tid & 63;
    float acc = 0.f;
#pragma unroll
    for (int i = 0; i < 4; ++i) acc += P.qhw[(size_t)qi * DD + l + 64 * i] * bufA[l + 64 * i];
    acc = wred(acc);
    if (l == 0) P.out[b * NQ + qi] = acc + P.qhb[qi];
  }
}

// ============================ kernels ======================================
__global__ __launch_bounds__(256) void k_gemm1w(TParams P) {
  __shared__ __align__(16) char smem[67584];
  wcast_phase(P, blockIdx.x, threadIdx.x);   // independent work, overlaps loads
  gemm_phase<false, 1>(smem, (const void*)P.x, P.f1w, P.f1b, P.eta1, blockIdx.x, threadIdx.x);
}
__global__ __launch_bounds__(256) void k_gemm2(TParams P) {
  __shared__ __align__(16) char smem[67584];
  gemm_phase<true, 0>(smem, (const void*)P.eta1, P.f2w, P.f2b, P.eta2, blockIdx.x, threadIdx.x);
}
__global__ __launch_bounds__(256) void k_grn(TParams P) {
  __shared__ __align__(16) char smem[79872];
  grn_phase(smem, P, blockIdx.x, threadIdx.x);
}
__global__ __launch_bounds__(256) void k_attn(TParams P) {
  __shared__ __align__(16) char smem[21504];
  attn_phase(smem, P, blockIdx.x, threadIdx.x);
}
__global__ __launch_bounds__(256) void k_tail(TParams P) {
  __shared__ __align__(16) char smem[11296];
  tail_phase(smem, P, blockIdx.x, threadIdx.x);
}

// ---------------------------------------------------------------------------
extern "C" void kernel_launch(void* const* d_in, const int* in_sizes, int n_in,
                              void* d_out, int out_size, void* d_ws, size_t ws_size,
                              hipStream_t stream)
{
  char* w8 = (char*)d_ws;
  TParams P;
  P.x     = (const float*)d_in[0];
  P.f1w   = (const float*)d_in[1];  P.f1b = (const float*)d_in[2];
  P.f2w   = (const float*)d_in[3];  P.f2b = (const float*)d_in[4];
  P.gw    = (const float*)d_in[5];  P.gb  = (const float*)d_in[6];
  P.lng   = (const float*)d_in[7];  P.lnb = (const float*)d_in[8];
  P.wq    = (const float*)d_in[9];
  P.wk    = (const float*)d_in[10];
  P.wv    = (const float*)d_in[11];
  P.wow   = (const float*)d_in[12]; P.wob = (const float*)d_in[13];
  P.alng  = (const float*)d_in[14]; P.alnb = (const float*)d_in[15];
  P.g2f1w = (const float*)d_in[16]; P.g2f1b = (const float*)d_in[17];
  P.g2f2w = (const float*)d_in[18]; P.g2f2b = (const float*)d_in[19];
  P.g2gw  = (const float*)d_in[20]; P.g2gb  = (const float*)d_in[21];
  P.g2lng = (const float*)d_in[22]; P.g2lnb = (const float*)d_in[23];
  P.qhw   = (const float*)d_in[24]; P.qhb   = (const float*)d_in[25];
  P.out   = (float*)d_out;

  P.wbf   = (u16*)(w8);                            // 5*128 KB bf16 tail weights
  P.p_eh  = (float*)(w8 + ((size_t)1 << 20));      // 1 MB
  P.p_den = (float*)(w8 + ((size_t)2100 << 10));   // 4 KB
  P.qkbuf = (float*)(w8 + ((size_t)2200 << 10));   // 8 KB
  P.eta1  = (u16*)(w8 + ((size_t)4  << 20));       // 4 MB
  P.eta2  = (u16*)(w8 + ((size_t)8  << 20));       // 4 MB
  P.hbuf  = (u16*)(w8 + ((size_t)12 << 20));       // 4 MB
  P.hlast = (float*)(w8 + ((size_t)16 << 20));     // 8 KB

  k_gemm1w<<<dim3(512), dim3(256), 0, stream>>>(P);
  k_gemm2 <<<dim3(512), dim3(256), 0, stream>>>(P);
  k_grn   <<<dim3(256), dim3(256), 0, stream>>>(P);
  k_attn  <<<dim3(256), dim3(256), 0, stream>>>(P);
  k_tail  <<<dim3(BB),  dim3(256), 0, stream>>>(P);
}

// Round 12
// 83.945 us; speedup vs baseline: 4.2334x; 1.6117x over previous
//
#include <hip/hip_runtime.h>
#include <hip/hip_bf16.h>
#include <math.h>

#define DD 256
#define BB 8
#define TT 1024
#define MM (BB*TT)
#define NH 4
#define DKH 64
#define NQ 3
#define SPLIT 32
#define SROWS (TT/SPLIT)   // 32

typedef __attribute__((ext_vector_type(8))) short bf16x8;
typedef __attribute__((ext_vector_type(4))) float f32x4;
typedef unsigned short u16;
typedef unsigned int u32;

__device__ __forceinline__ float bf2f(u16 u) {
  return __uint_as_float(((u32)u) << 16);
}
__device__ __forceinline__ u16 f2bf(float x) {
  __hip_bfloat16 h = __float2bfloat16(x);
  return *reinterpret_cast<u16*>(&h);
}
__device__ __forceinline__ uint2 pack4(float a, float b, float c, float d) {
  uint2 r;
  r.x = (u32)f2bf(a) | ((u32)f2bf(b) << 16);
  r.y = (u32)f2bf(c) | ((u32)f2bf(d) << 16);
  return r;
}
__device__ __forceinline__ float wred(float v) {
#pragma unroll
  for (int off = 32; off; off >>= 1) v += __shfl_xor(v, off);
  return v;
}

struct TParams {
  const float* x;
  const float* f1w; const float* f1b;
  const float* f2w; const float* f2b;
  const float* gw;  const float* gb;
  const float* lng; const float* lnb;
  const float* wq;  const float* wk;  const float* wv;
  const float* wow; const float* wob;
  const float* alng; const float* alnb;
  const float* g2f1w; const float* g2f1b;
  const float* g2f2w; const float* g2f2b;
  const float* g2gw;  const float* g2gb;
  const float* g2lng; const float* g2lnb;
  const float* qhw;   const float* qhb;
  u16* eta1; u16* eta2; u16* hbuf; float* hlast;
  float* qkbuf; u16* wbf; float* p_eh; float* p_den;
  float* out;
};

// ============================ phase: 64x64 GEMM ============================
template<bool ABF, int ACT>
__device__ __forceinline__ void gemm_phase(char* smem, const void* A_,
                                           const float* W, const float* bias,
                                           u16* out, int bid, int tid)
{
  u16 (*As)[264] = reinterpret_cast<u16(*)[264]>(smem);
  u16 (*Bs)[264] = reinterpret_cast<u16(*)[264]>(smem + 33792);
  const int lane = tid & 63, wave = tid >> 6;
  const int wr = wave >> 1, wc = wave & 1;
  const int q  = lane >> 4, lr = lane & 15;
  const int m0 = (bid >> 2) * 64, n0 = (bid & 3) * 64;

#pragma unroll
  for (int p = 0; p < 8; ++p) {
    const int c = tid + p * 256;
    const int row = c >> 5, col = (c & 31) * 8;
    if constexpr (ABF) {
      *(uint4*)&As[row][col] = *(const uint4*)((const u16*)A_ + (size_t)(m0 + row) * DD + col);
    } else {
      const float* ap = (const float*)A_ + (size_t)(m0 + row) * DD + col;
      const float4 v0 = *(const float4*)ap, v1 = *(const float4*)(ap + 4);
      *(uint2*)&As[row][col]     = pack4(v0.x, v0.y, v0.z, v0.w);
      *(uint2*)&As[row][col + 4] = pack4(v1.x, v1.y, v1.z, v1.w);
    }
    const float* wp = W + (size_t)(n0 + row) * DD + col;
    const float4 w0 = *(const float4*)wp, w1 = *(const float4*)(wp + 4);
    *(uint2*)&Bs[row][col]     = pack4(w0.x, w0.y, w0.z, w0.w);
    *(uint2*)&Bs[row][col + 4] = pack4(w1.x, w1.y, w1.z, w1.w);
  }
  __syncthreads();

  f32x4 acc[2][2] = {};
#pragma unroll
  for (int kk = 0; kk < 8; ++kk) {
    const int koff = kk * 32 + q * 8;
    bf16x8 av[2], bv[2];
    av[0] = *(const bf16x8*)&As[wr * 32 + lr][koff];
    av[1] = *(const bf16x8*)&As[wr * 32 + 16 + lr][koff];
    bv[0] = *(const bf16x8*)&Bs[wc * 32 + lr][koff];
    bv[1] = *(const bf16x8*)&Bs[wc * 32 + 16 + lr][koff];
#pragma unroll
    for (int i = 0; i < 2; ++i)
#pragma unroll
      for (int j = 0; j < 2; ++j)
        acc[i][j] = __builtin_amdgcn_mfma_f32_16x16x32_bf16(av[i], bv[j], acc[i][j], 0, 0, 0);
  }

#pragma unroll
  for (int i = 0; i < 2; ++i) {
#pragma unroll
    for (int j = 0; j < 2; ++j) {
      const int col = n0 + wc * 32 + j * 16 + lr;
      const float bvv = bias ? bias[col] : 0.f;
#pragma unroll
      for (int t = 0; t < 4; ++t) {
        const int row = m0 + wr * 32 + i * 16 + q * 4 + t;
        float v = acc[i][j][t] + bvv;
        if (ACT == 1) v = v > 0.f ? v : expm1f(v);
        out[(size_t)row * DD + col] = f2bf(v);
      }
    }
  }
}

// ============================ phase: GRN gate+LN (+qk) =====================
__device__ __forceinline__ void grn_phase(char* smem, const TParams& P, int bid, int tid)
{
  u16 (*As)[136] = reinterpret_cast<u16(*)[136]>(smem);
  u16 (*Bs)[136] = reinterpret_cast<u16(*)[136]>(smem + 8704);
  float (*red_s)[5] = reinterpret_cast<float(*)[5]>(smem + 78336);
  float (*red_q)[5] = reinterpret_cast<float(*)[5]>(smem + 78976);
  float* smean = reinterpret_cast<float*>(smem + 79616);
  float* srstd = reinterpret_cast<float*>(smem + 79744);
  float* hlp   = reinterpret_cast<float*>(smem);          // aliases As (dead after loop)
  float* qv    = reinterpret_cast<float*>(smem + 1024);   // aliases As (dead after loop)

  const int lane = tid & 63, wave = tid >> 6;
  const int q  = lane >> 4, lr = lane & 15;
  const int m0 = bid * 32;
  const bool isqk = ((bid & 31) == 31);

  f32x4 acc[2][4] = {};

  for (int k0 = 0; k0 < DD; k0 += 128) {
#pragma unroll
    for (int p = 0; p < 2; ++p) {
      const int c = tid + p * 256;
      const int row = c >> 4, col = (c & 15) * 8;
      *(uint4*)&As[row][col] = *(const uint4*)(P.eta2 + (size_t)(m0 + row) * DD + k0 + col);
    }
#pragma unroll
    for (int p = 0; p < 16; ++p) {
      const int c = tid + p * 256;
      const int row = c >> 4, col = (c & 15) * 8;
      const float* wp = P.gw + (size_t)row * DD + k0 + col;
      const float4 w0 = *(const float4*)wp, w1 = *(const float4*)(wp + 4);
      *(uint2*)&Bs[row][col]     = pack4(w0.x, w0.y, w0.z, w0.w);
      *(uint2*)&Bs[row][col + 4] = pack4(w1.x, w1.y, w1.z, w1.w);
    }
    __syncthreads();
#pragma unroll
    for (int kk = 0; kk < 4; ++kk) {
      const int koff = kk * 32 + q * 8;
      bf16x8 av[2], bv[4];
#pragma unroll
      for (int i = 0; i < 2; ++i) av[i] = *(const bf16x8*)&As[i * 16 + lr][koff];
#pragma unroll
      for (int j = 0; j < 4; ++j) bv[j] = *(const bf16x8*)&Bs[wave * 64 + j * 16 + lr][koff];
#pragma unroll
      for (int i = 0; i < 2; ++i)
#pragma unroll
        for (int j = 0; j < 4; ++j)
          acc[i][j] = __builtin_amdgcn_mfma_f32_16x16x32_bf16(av[i], bv[j], acc[i][j], 0, 0, 0);
    }
    __syncthreads();
  }

  float pre[2][4][4];
#pragma unroll
  for (int i = 0; i < 2; ++i) {
#pragma unroll
    for (int j = 0; j < 4; ++j) {
      const int n = wave * 64 + j * 16 + lr;
      const float gbn = P.gb[n];
#pragma unroll
      for (int t = 0; t < 4; ++t) {
        const int grow = m0 + i * 16 + q * 4 + t;
        const float gate = acc[i][j][t] + gbn;
        const float sig = 1.f / (1.f + expf(-gate));
        const float e2 = bf2f(P.eta2[(size_t)grow * DD + n]);
        pre[i][j][t] = P.x[(size_t)grow * DD + n] + sig * e2;
      }
    }
  }
#pragma unroll
  for (int i = 0; i < 2; ++i) {
#pragma unroll
    for (int t = 0; t < 4; ++t) {
      float s = 0.f, sq = 0.f;
#pragma unroll
      for (int j = 0; j < 4; ++j) { const float v = pre[i][j][t]; s += v; sq += v * v; }
#pragma unroll
      for (int m = 1; m <= 8; m <<= 1) { s += __shfl_xor(s, m); sq += __shfl_xor(sq, m); }
      if (lr == 0) {
        const int ml = i * 16 + q * 4 + t;
        red_s[ml][wave] = s;
        red_q[ml][wave] = sq;
      }
    }
  }
  __syncthreads();
  if (tid < 32) {
    const float s  = red_s[tid][0] + red_s[tid][1] + red_s[tid][2] + red_s[tid][3];
    const float sq = red_q[tid][0] + red_q[tid][1] + red_q[tid][2] + red_q[tid][3];
    const float mean = s * (1.f / DD);
    const float var = sq * (1.f / DD) - mean * mean;
    smean[tid] = mean;
    srstd[tid] = rsqrtf(var + 1e-5f);
  }
  __syncthreads();
#pragma unroll
  for (int i = 0; i < 2; ++i) {
#pragma unroll
    for (int j = 0; j < 4; ++j) {
      const int n = wave * 64 + j * 16 + lr;
      const float gn = P.lng[n], bn = P.lnb[n];
#pragma unroll
      for (int t = 0; t < 4; ++t) {
        const int ml = i * 16 + q * 4 + t;
        const int grow = m0 + ml;
        const float hn = (pre[i][j][t] - smean[ml]) * srstd[ml] * gn + bn;
        P.hbuf[(size_t)grow * DD + n] = f2bf(hn);
        if (isqk && ml == 31) {
          P.hlast[(size_t)(grow >> 10) * DD + n] = hn;
          hlp[n] = hn;
        }
      }
    }
  }

  if (isqk) {
    __syncthreads();
    const int b = bid >> 5;
    {
      const int j = tid >> 2, seg = tid & 3;
      const float* sp = hlp + seg * 64;
#pragma unroll
      for (int pass = 0; pass < 4; ++pass) {
        const int r = pass * 64 + j;
        const float* wr_ = P.wq + (size_t)r * DD + seg * 64;
        float acc2 = 0.f;
#pragma unroll
        for (int k = 0; k < 64; k += 4) {
          const float4 w4 = *(const float4*)(wr_ + k);
          acc2 += w4.x * sp[k] + w4.y * sp[k + 1] + w4.z * sp[k + 2] + w4.w * sp[k + 3];
        }
        acc2 += __shfl_xor(acc2, 1);
        acc2 += __shfl_xor(acc2, 2);
        if (seg == 0) qv[r] = acc2;
      }
    }
    __syncthreads();
#pragma unroll
    for (int h = 0; h < NH; ++h) {
      float acc2 = 0.f;
      const float* wkb = P.wk + (size_t)(h * DKH) * DD + tid;
#pragma unroll 8
      for (int d = 0; d < DKH; ++d)
        acc2 += qv[h * DKH + d] * wkb[(size_t)d * DD];
      P.qkbuf[((size_t)b * NH + h) * DD + tid] = acc2 * 0.125f;
    }
  }
}

// ============================ phase: tail-weight cast ======================
__device__ __forceinline__ void wcast_phase(const TParams& P, int cb, int tid)
{
  const int base = cb * 640;
#pragma unroll
  for (int r = 0; r < 3; ++r) {
    const int k = r * 256 + tid;
    if (k < 640) {
      const int e = base + k;
      const int mi = e >> 16, off = e & 65535;
      const float* s = (mi == 0) ? P.wow : (mi == 1) ? P.g2f1w : (mi == 2) ? P.g2f2w
                     : (mi == 3) ? P.g2gw : P.wv;
      P.wbf[e] = f2bf(s[off]);
    }
  }
}

// ============================ phase: attention partials ====================
__device__ __forceinline__ void attn_phase(char* smem, const TParams& P, int bid, int tid)
{
  float (*qk4)[DD] = reinterpret_cast<float(*)[DD]>(smem);
  u16 (*hch)[264]  = reinterpret_cast<u16(*)[264]>(smem + 4096);
  float (*E)[NH]   = reinterpret_cast<float(*)[NH]>(smem + 20992);
  const int chunk = bid & 31, b = bid >> 5;

#pragma unroll
  for (int h = 0; h < NH; ++h)
    qk4[h][tid] = P.qkbuf[((size_t)b * NH + h) * DD + tid];
#pragma unroll
  for (int p = 0; p < 4; ++p) {
    const int idx = p * 256 + tid;
    const int row = idx >> 5, col = (idx & 31) * 8;
    *(uint4*)&hch[row][col] =
        *(const uint4*)(P.hbuf + ((size_t)(b * TT + chunk * SROWS + row)) * DD + col);
  }
  __syncthreads();

  {
    const int s = tid >> 3, sub = tid & 7;
    const u16* hp = &hch[s][sub * 32];
    float part[NH] = {};
#pragma unroll
    for (int v = 0; v < 4; ++v) {
      const bf16x8 h8 = *(const bf16x8*)(hp + v * 8);
      float hf[8];
#pragma unroll
      for (int e = 0; e < 8; ++e) hf[e] = bf2f((u16)h8[e]);
#pragma unroll
      for (int h = 0; h < NH; ++h) {
        const float* qp = &qk4[h][sub * 32 + v * 8];
#pragma unroll
        for (int e = 0; e < 8; ++e) part[h] += hf[e] * qp[e];
      }
    }
#pragma unroll
    for (int h = 0; h < NH; ++h) {
      float p = part[h];
      p += __shfl_xor(p, 1);
      p += __shfl_xor(p, 2);
      p += __shfl_xor(p, 4);
      if (sub == 0) E[s][h] = __expf(fminf(fmaxf(p, -30.f), 30.f));
    }
  }
  __syncthreads();

  {
    float eh[NH] = {};
    for (int s = 0; s < SROWS; ++s) {
      const float hv = bf2f(hch[s][tid]);
      const float4 E4 = *(const float4*)&E[s][0];
      eh[0] += E4.x * hv; eh[1] += E4.y * hv;
      eh[2] += E4.z * hv; eh[3] += E4.w * hv;
    }
    const size_t pb = ((size_t)(b * SPLIT + chunk)) * NH * DD;
#pragma unroll
    for (int h = 0; h < NH; ++h) P.p_eh[pb + h * DD + tid] = eh[h];
  }
  if (tid < NH) {
    float s = 0.f;
    for (int s2 = 0; s2 < SROWS; ++s2) s += E[s2][tid];
    P.p_den[(b * SPLIT + chunk) * NH + tid] = s;
  }
}

// ============================ kernels ======================================
__global__ __launch_bounds__(256) void k_gemm1w(TParams P) {
  __shared__ __align__(16) char smem[67584];
  wcast_phase(P, blockIdx.x, threadIdx.x);   // independent work, overlaps loads
  gemm_phase<false, 1>(smem, (const void*)P.x, P.f1w, P.f1b, P.eta1, blockIdx.x, threadIdx.x);
}
__global__ __launch_bounds__(256) void k_gemm2(TParams P) {
  __shared__ __align__(16) char smem[67584];
  gemm_phase<true, 0>(smem, (const void*)P.eta1, P.f2w, P.f2b, P.eta2, blockIdx.x, threadIdx.x);
}
__global__ __launch_bounds__(256) void k_grn(TParams P) {
  __shared__ __align__(16) char smem[79872];
  grn_phase(smem, P, blockIdx.x, threadIdx.x);
}
__global__ __launch_bounds__(256) void k_attn(TParams P) {
  __shared__ __align__(16) char smem[21504];
  attn_phase(smem, P, blockIdx.x, threadIdx.x);
}

// ============================ tail: 1024 threads (proven R8/R9 form) =======
__device__ __forceinline__ void mv256b(const u16* __restrict__ W16,
                                       const float* __restrict__ srcbuf,
                                       float* __restrict__ dst,
                                       int wave, int lane)
{
  const int half = lane >> 5, l32 = lane & 31;
  float s[8];
  {
    const float4 s0 = *(const float4*)(srcbuf + l32 * 8);
    const float4 s1 = *(const float4*)(srcbuf + l32 * 8 + 4);
    s[0] = s0.x; s[1] = s0.y; s[2] = s0.z; s[3] = s0.w;
    s[4] = s1.x; s[5] = s1.y; s[6] = s1.z; s[7] = s1.w;
  }
#pragma unroll
  for (int i = 0; i < 8; ++i) {
    const int r = wave * 16 + i * 2 + half;
    const bf16x8 wv = *(const bf16x8*)(W16 + (size_t)r * DD + l32 * 8);
    float acc = 0.f;
#pragma unroll
    for (int e = 0; e < 8; ++e) acc += bf2f((u16)wv[e]) * s[e];
#pragma unroll
    for (int off = 16; off; off >>= 1) acc += __shfl_xor(acc, off);
    if (l32 == 0) dst[r] = acc;
  }
}

#define LN_STEP(val, gam, bet, dst) \
  __syncthreads(); \
  if (tid < DD) { lnS[tid] = (val); lnQ[tid] = (val) * (val); } \
  __syncthreads(); \
  if (tid < 64) { \
    float s_ = 0.f, q_ = 0.f; \
    _Pragma("unroll") \
    for (int i_ = 0; i_ < 4; ++i_) { s_ += lnS[tid + 64 * i_]; q_ += lnQ[tid + 64 * i_]; } \
    s_ = wred(s_); q_ = wred(q_); \
    if (tid == 0) { const float m_ = s_ * (1.f / DD); red2[0] = m_; red2[1] = rsqrtf(q_ * (1.f / DD) - m_ * m_ + 1e-5f); } \
  } \
  __syncthreads(); \
  if (tid < DD) dst[tid] = ((val) - red2[0]) * red2[1] * gam[tid] + bet[tid]; \
  __syncthreads();

__global__ __launch_bounds__(1024) void k_tail(TParams P)
{
  __shared__ float pv[NH * DD];
  __shared__ float den[NH];
  __shared__ float hl[DD], bufA[DD], bufB[DD], bufC[DD], part0[DD];
  __shared__ float lnS[DD], lnQ[DD];
  __shared__ float red2[2];
  const int b = blockIdx.x, tid = threadIdx.x;
  const int wave = tid >> 6, lane = tid & 63;
  const int half = lane >> 5, l32 = lane & 31;

  // reduce partials
  float ehsum = 0.f;
  for (int c = 0; c < SPLIT; ++c)
    ehsum += P.p_eh[((size_t)(b * SPLIT + c)) * NH * DD + tid];
  if (tid < NH) {
    float s = 0.f;
    for (int c = 0; c < SPLIT; ++c) s += P.p_den[(b * SPLIT + c) * NH + tid];
    den[tid] = s;
  }
  if (tid < DD) hl[tid] = P.hlast[(size_t)b * DD + tid];
  __syncthreads();
  pv[tid] = ehsum / den[tid >> 8];
  __syncthreads();

  // ctx[r] = sum_e pv[(r>>6)*256+e] * wv[r][e] -> bufB (16 waves x 16 rows)
  {
    const u16* wv16 = P.wbf + 4 * 65536;
#pragma unroll
    for (int i = 0; i < 8; ++i) {
      const int r = wave * 16 + i * 2 + half;
      const float* sp = pv + (r >> 6) * DD + l32 * 8;
      const float4 s0 = *(const float4*)sp;
      const float4 s1 = *(const float4*)(sp + 4);
      const bf16x8 wvv = *(const bf16x8*)(wv16 + (size_t)r * DD + l32 * 8);
      float acc = bf2f((u16)wvv[0]) * s0.x + bf2f((u16)wvv[1]) * s0.y
                + bf2f((u16)wvv[2]) * s0.z + bf2f((u16)wvv[3]) * s0.w
                + bf2f((u16)wvv[4]) * s1.x + bf2f((u16)wvv[5]) * s1.y
                + bf2f((u16)wvv[6]) * s1.z + bf2f((u16)wvv[7]) * s1.w;
#pragma unroll
      for (int off = 16; off; off >>= 1) acc += __shfl_xor(acc, off);
      if (l32 == 0) bufB[r] = acc;
    }
  }
  __syncthreads();

  // out proj + residual + LN -> bufA (h2)
  mv256b(P.wbf + 0 * 65536, bufB, part0, wave, lane);
  __syncthreads();
  float v = 0.f;
  if (tid < DD) v = hl[tid] + part0[tid] + P.wob[tid];
  LN_STEP(v, P.alng, P.alnb, bufA)

  // f1 + ELU -> bufB
  mv256b(P.wbf + 1 * 65536, bufA, part0, wave, lane);
  __syncthreads();
  if (tid < DD) {
    const float e1 = part0[tid] + P.g2f1b[tid];
    bufB[tid] = e1 > 0.f ? e1 : expm1f(e1);
  }
  __syncthreads();

  // f2 -> bufC (eta2)
  mv256b(P.wbf + 2 * 65536, bufB, part0, wave, lane);
  __syncthreads();
  if (tid < DD) bufC[tid] = part0[tid] + P.g2f2b[tid];
  __syncthreads();

  // gate + residual + LN -> bufA (h3)
  mv256b(P.wbf + 3 * 65536, bufC, part0, wave, lane);
  __syncthreads();
  v = 0.f;
  if (tid < DD) {
    const float g = part0[tid] + P.g2gb[tid];
    v = bufA[tid] + (1.f / (1.f + expf(-g))) * bufC[tid];
  }
  LN_STEP(v, P.g2lng, P.g2lnb, bufA)

  // quantile head
  if (tid < 64 * NQ) {
    const int qi = tid >> 6, l = tid & 63;
    float acc = 0.f;
#pragma unroll
    for (int i = 0; i < 4; ++i) acc += P.qhw[(size_t)qi * DD + l + 64 * i] * bufA[l + 64 * i];
    acc = wred(acc);
    if (l == 0) P.out[b * NQ + qi] = acc + P.qhb[qi];
  }
}

// ---------------------------------------------------------------------------
extern "C" void kernel_launch(void* const* d_in, const int* in_sizes, int n_in,
                              void* d_out, int out_size, void* d_ws, size_t ws_size,
                              hipStream_t stream)
{
  char* w8 = (char*)d_ws;
  TParams P;
  P.x     = (const float*)d_in[0];
  P.f1w   = (const float*)d_in[1];  P.f1b = (const float*)d_in[2];
  P.f2w   = (const float*)d_in[3];  P.f2b = (const float*)d_in[4];
  P.gw    = (const float*)d_in[5];  P.gb  = (const float*)d_in[6];
  P.lng   = (const float*)d_in[7];  P.lnb = (const float*)d_in[8];
  P.wq    = (const float*)d_in[9];
  P.wk    = (const float*)d_in[10];
  P.wv    = (const float*)d_in[11];
  P.wow   = (const float*)d_in[12]; P.wob = (const float*)d_in[13];
  P.alng  = (const float*)d_in[14]; P.alnb = (const float*)d_in[15];
  P.g2f1w = (const float*)d_in[16]; P.g2f1b = (const float*)d_in[17];
  P.g2f2w = (const float*)d_in[18]; P.g2f2b = (const float*)d_in[19];
  P.g2gw  = (const float*)d_in[20]; P.g2gb  = (const float*)d_in[21];
  P.g2lng = (const float*)d_in[22]; P.g2lnb = (const float*)d_in[23];
  P.qhw   = (const float*)d_in[24]; P.qhb   = (const float*)d_in[25];
  P.out   = (float*)d_out;

  P.wbf   = (u16*)(w8);                            // 5*128 KB bf16 tail weights
  P.p_eh  = (float*)(w8 + ((size_t)1 << 20));      // 1 MB
  P.p_den = (float*)(w8 + ((size_t)2100 << 10));   // 4 KB
  P.qkbuf = (float*)(w8 + ((size_t)2200 << 10));   // 8 KB
  P.eta1  = (u16*)(w8 + ((size_t)4  << 20));       // 4 MB
  P.eta2  = (u16*)(w8 + ((size_t)8  << 20));       // 4 MB
  P.hbuf  = (u16*)(w8 + ((size_t)12 << 20));       // 4 MB
  P.hlast = (float*)(w8 + ((size_t)16 << 20));     // 8 KB

  k_gemm1w<<<dim3(512), dim3(256),  0, stream>>>(P);
  k_gemm2 <<<dim3(512), dim3(256),  0, stream>>>(P);
  k_grn   <<<dim3(256), dim3(256),  0, stream>>>(P);
  k_attn  <<<dim3(256), dim3(256),  0, stream>>>(P);
  k_tail  <<<dim3(BB),  dim3(1024), 0, stream>>>(P);
}